// Round 6
// baseline (449.872 us; speedup 1.0000x reference)
//
#include <hip/hip_runtime.h>
#include <hip/hip_bf16.h>

#define C_DIM 512
#define HW    4096
#define BATCH 4
#define PW    66
#define PPIX  (PW*PW)   // 4356

typedef __attribute__((ext_vector_type(8))) short bf16x8;
typedef __attribute__((ext_vector_type(4))) float f32x4;
typedef __attribute__((ext_vector_type(16))) float f32x16;

static __device__ __forceinline__ short f2b(float f) {
    union { float f; unsigned u; } v; v.f = f;
    unsigned r = v.u + 0x7fffu + ((v.u >> 16) & 1u);
    return (short)(r >> 16);
}
static __device__ __forceinline__ float b2f(short s) {
    union { unsigned u; float f; } v; v.u = ((unsigned)(unsigned short)s) << 16;
    return v.f;
}

static __device__ __forceinline__ f32x4 zero4() {
    f32x4 v = {0.f, 0.f, 0.f, 0.f};
    return v;
}
static __device__ __forceinline__ f32x16 zero16() {
    f32x16 v = {0.f,0.f,0.f,0.f, 0.f,0.f,0.f,0.f, 0.f,0.f,0.f,0.f, 0.f,0.f,0.f,0.f};
    return v;
}

static __device__ __forceinline__ void gload16(const void* g, void* l) {
    __builtin_amdgcn_global_load_lds(
        (__attribute__((address_space(1))) void*)g,
        (__attribute__((address_space(3))) void*)l, 16, 0, 0);
}

// ---------------- weight prep ----------------
__global__ void k_cvt_bf16(const float* __restrict__ in, short* __restrict__ out, int n) {
    int i = blockIdx.x * 256 + threadIdx.x;
    if (i < n) out[i] = f2b(in[i]);
}

__global__ void k_reorder_w3(const float* __restrict__ w, short* __restrict__ out) {
    int i = blockIdx.x * 256 + threadIdx.x;
    int c   = i & 511;
    int tap = (i >> 9) % 9;
    int o   = i / (9 * 512);
    out[i] = f2b(w[((size_t)o * 512 + c) * 9 + tap]);
}

// ---------------- layernorm ----------------
__global__ void k_ln_stats(const float* __restrict__ x, float* __restrict__ mean,
                           float* __restrict__ rstd) {
    __shared__ float ss[8][32];
    __shared__ float sq2[8][32];
    int bid = blockIdx.x;
    int t = threadIdx.x;
    int px = t & 31, cg = t >> 5;
    int p = bid * 32 + px;
    int b = p >> 12, pix = p & 4095;
    const float* xp = x + (size_t)b * C_DIM * HW + pix;
    float s = 0.f, sq = 0.f;
    #pragma unroll 4
    for (int c = cg * 64; c < cg * 64 + 64; ++c) {
        float v = xp[(size_t)c * HW];
        s += v; sq += v * v;
    }
    ss[cg][px] = s;
    sq2[cg][px] = sq;
    __syncthreads();
    if (t < 32) {
        float S = 0.f, Q = 0.f;
        #pragma unroll
        for (int j = 0; j < 8; ++j) { S += ss[j][t]; Q += sq2[j][t]; }
        float mu  = S * (1.0f / C_DIM);
        float var = Q * (1.0f / C_DIM) - mu * mu;
        int pg = bid * 32 + t;
        mean[pg] = mu;
        rstd[pg] = 1.0f / sqrtf(var + 1e-6f);
    }
}

__global__ void k_ln_apply(const float* __restrict__ x, const float* __restrict__ mean,
                           const float* __restrict__ rstd, const float* __restrict__ lnw,
                           const float* __restrict__ lnb, short* __restrict__ hp) {
    __shared__ short tile[64][65];
    int bid = blockIdx.x;
    int ct = bid & 7, y = (bid >> 3) & 63, b = bid >> 9;
    int c0 = ct * 64, p0 = y * 64;
    int t = threadIdx.x;
    int pi = t & 63, ci0 = t >> 6;
    int pg = (b << 12) + p0 + pi;
    float mu = mean[pg], rs = rstd[pg];
    const float* xb = x + (size_t)b * C_DIM * HW;
    #pragma unroll
    for (int cc = 0; cc < 64; cc += 4) {
        int c = c0 + cc + ci0;
        float v = xb[(size_t)c * HW + p0 + pi];
        tile[cc + ci0][pi] = f2b((v - mu) * rs * lnw[c] + lnb[c]);
    }
    __syncthreads();
    int cj = t & 63, pj = t >> 6;
    #pragma unroll
    for (int pp = 0; pp < 64; pp += 4) {
        int pidx = pp + pj;
        size_t dst = ((size_t)b * PPIX + (size_t)(y + 1) * PW + 1 + pidx) * C_DIM + c0 + cj;
        hp[dst] = tile[cj][pidx];
    }
}

// ---------------- conv-as-GEMM (q and proj) ----------------
template<int TAPS, int GMODE, int EPI>
__global__ __launch_bounds__(256, 2) void k_gemm(
        const short* __restrict__ A, const short* __restrict__ Bw,
        void* __restrict__ Out, const float* __restrict__ bias,
        const float* __restrict__ resid)
{
    constexpr int K = TAPS * 512;
    constexpr int NKC = K / 64;
    __shared__ short Alds[128 * 64];
    __shared__ short Blds[128 * 64];
    int bid = blockIdx.x;
    int mt = bid & 31, nt = (bid >> 5) & 3, b = bid >> 7;
    int m0 = mt * 128, n0 = nt * 128;
    int t = threadIdx.x;
    int lane = t & 63, w = t >> 6;
    int wm = w >> 1, wn = w & 1;
    int g = lane >> 4, li = lane & 15;
    int srow = t >> 3, schunk = t & 7;
    const short* Ab = A + (GMODE == 0 ? (size_t)b * PPIX * C_DIM : (size_t)b * HW * C_DIM);

    f32x4 acc[4][4];
    #pragma unroll
    for (int i = 0; i < 4; ++i)
        #pragma unroll
        for (int j = 0; j < 4; ++j) acc[i][j] = zero4();

    for (int kc = 0; kc < NKC; ++kc) {
        int tap = (TAPS == 9) ? (kc >> 3) : 4;
        int cb  = (kc & 7) * 64;
        __syncthreads();
        #pragma unroll
        for (int r = 0; r < 4; ++r) {
            int row = r * 32 + srow;
            size_t goff;
            if (GMODE == 0) {
                int m = m0 + row;
                int yy = m >> 6, xx = m & 63;
                int pp = (yy + tap / 3) * PW + xx + (tap % 3);
                goff = (size_t)pp * C_DIM + cb + schunk * 8;
            } else {
                goff = (size_t)(m0 + row) * K + kc * 64 + schunk * 8;
            }
            gload16(Ab + goff, Alds + row * 64 + schunk * 8);
        }
        #pragma unroll
        for (int r = 0; r < 4; ++r) {
            int row = r * 32 + srow;
            size_t goff = (size_t)(n0 + row) * K + kc * 64 + schunk * 8;
            gload16(Bw + goff, Blds + row * 64 + schunk * 8);
        }
        __syncthreads();
        #pragma unroll
        for (int ks = 0; ks < 2; ++ks) {
            int koff = ks * 32 + g * 8;
            bf16x8 af[4], bfr[4];
            #pragma unroll
            for (int i = 0; i < 4; ++i)
                af[i] = *(const bf16x8*)&Alds[(wm * 64 + i * 16 + li) * 64 + koff];
            #pragma unroll
            for (int j = 0; j < 4; ++j)
                bfr[j] = *(const bf16x8*)&Blds[(wn * 64 + j * 16 + li) * 64 + koff];
            #pragma unroll
            for (int i = 0; i < 4; ++i)
                #pragma unroll
                for (int j = 0; j < 4; ++j)
                    acc[i][j] = __builtin_amdgcn_mfma_f32_16x16x32_bf16(af[i], bfr[j], acc[i][j], 0, 0, 0);
        }
    }
    #pragma unroll
    for (int fm = 0; fm < 4; ++fm) {
        #pragma unroll
        for (int fn = 0; fn < 4; ++fn) {
            int mrow = m0 + wm * 64 + fm * 16 + g * 4;
            int ncol = n0 + wn * 64 + fn * 16 + li;
            if constexpr (EPI == 0) {
                #pragma unroll
                for (int i = 0; i < 4; ++i) {
                    size_t dst = ((size_t)b * HW + mrow + i) * C_DIM + ncol;
                    ((short*)Out)[dst] = f2b(acc[fm][fn][i]);
                }
            } else if constexpr (EPI == 1) {
                size_t dst = ((size_t)b * C_DIM + ncol) * HW + mrow;
                short4 sv = make_short4(f2b(acc[fm][fn][0]), f2b(acc[fm][fn][1]),
                                        f2b(acc[fm][fn][2]), f2b(acc[fm][fn][3]));
                *(short4*)((short*)Out + dst) = sv;
            } else {
                size_t dst = ((size_t)b * C_DIM + ncol) * HW + mrow;
                float bb = bias[ncol];
                float4 xr = *(const float4*)(resid + dst);
                float4 o;
                o.x = acc[fm][fn][0] + bb + xr.x;
                o.y = acc[fm][fn][1] + bb + xr.y;
                o.z = acc[fm][fn][2] + bb + xr.z;
                o.w = acc[fm][fn][3] + bb + xr.w;
                *(float4*)((float*)Out + dst) = o;
            }
        }
    }
}

// ---------------- fused K+V 3x3 conv ----------------
__global__ __launch_bounds__(256, 2) void k_gemm_kv(
        const short* __restrict__ A, const short* __restrict__ Bk,
        const short* __restrict__ Bv, short* __restrict__ OutK,
        short* __restrict__ OutV)
{
    constexpr int K = 4608;
    __shared__ short Alds[128 * 64];
    __shared__ short Bklds[128 * 64];
    __shared__ short Bvlds[128 * 64];
    int bid = blockIdx.x;
    int mt = bid & 31, nt = (bid >> 5) & 3, b = bid >> 7;
    int m0 = mt * 128, n0 = nt * 128;
    int t = threadIdx.x;
    int lane = t & 63, w = t >> 6;
    int wm = w >> 1, wn = w & 1;
    int g = lane >> 4, li = lane & 15;
    int srow = t >> 3, schunk = t & 7;
    const short* Ab = A + (size_t)b * PPIX * C_DIM;

    f32x4 accK[4][4], accV[4][4];
    #pragma unroll
    for (int i = 0; i < 4; ++i)
        #pragma unroll
        for (int j = 0; j < 4; ++j) { accK[i][j] = zero4(); accV[i][j] = zero4(); }

    for (int kc = 0; kc < 72; ++kc) {
        int tap = kc >> 3;
        int cb  = (kc & 7) * 64;
        __syncthreads();
        #pragma unroll
        for (int r = 0; r < 4; ++r) {
            int row = r * 32 + srow;
            int m = m0 + row;
            int yy = m >> 6, xx = m & 63;
            int pp = (yy + tap / 3) * PW + xx + (tap % 3);
            gload16(Ab + (size_t)pp * C_DIM + cb + schunk * 8, Alds + row * 64 + schunk * 8);
        }
        #pragma unroll
        for (int r = 0; r < 4; ++r) {
            int row = r * 32 + srow;
            size_t goff = (size_t)(n0 + row) * K + kc * 64 + schunk * 8;
            gload16(Bk + goff, Bklds + row * 64 + schunk * 8);
            gload16(Bv + goff, Bvlds + row * 64 + schunk * 8);
        }
        __syncthreads();
        #pragma unroll
        for (int ks = 0; ks < 2; ++ks) {
            int koff = ks * 32 + g * 8;
            bf16x8 af[4], bk[4], bv[4];
            #pragma unroll
            for (int i = 0; i < 4; ++i)
                af[i] = *(const bf16x8*)&Alds[(wm * 64 + i * 16 + li) * 64 + koff];
            #pragma unroll
            for (int j = 0; j < 4; ++j)
                bk[j] = *(const bf16x8*)&Bklds[(wn * 64 + j * 16 + li) * 64 + koff];
            #pragma unroll
            for (int i = 0; i < 4; ++i)
                #pragma unroll
                for (int j = 0; j < 4; ++j)
                    accK[i][j] = __builtin_amdgcn_mfma_f32_16x16x32_bf16(af[i], bk[j], accK[i][j], 0, 0, 0);
            #pragma unroll
            for (int j = 0; j < 4; ++j)
                bv[j] = *(const bf16x8*)&Bvlds[(wn * 64 + j * 16 + li) * 64 + koff];
            #pragma unroll
            for (int i = 0; i < 4; ++i)
                #pragma unroll
                for (int j = 0; j < 4; ++j)
                    accV[i][j] = __builtin_amdgcn_mfma_f32_16x16x32_bf16(af[i], bv[j], accV[i][j], 0, 0, 0);
        }
    }
    #pragma unroll
    for (int fm = 0; fm < 4; ++fm) {
        #pragma unroll
        for (int fn = 0; fn < 4; ++fn) {
            int mrow = m0 + wm * 64 + fm * 16 + g * 4;
            int ncol = n0 + wn * 64 + fn * 16 + li;
            #pragma unroll
            for (int i = 0; i < 4; ++i) {
                size_t dst = ((size_t)b * HW + mrow + i) * C_DIM + ncol;
                OutK[dst] = f2b(accK[fm][fn][i]);
            }
            size_t dstv = ((size_t)b * C_DIM + ncol) * HW + mrow;
            short4 sv = make_short4(f2b(accV[fm][fn][0]), f2b(accV[fm][fn][1]),
                                    f2b(accV[fm][fn][2]), f2b(accV[fm][fn][3]));
            *(short4*)(OutV + dstv) = sv;
        }
    }
}

// ---------------- flash attention, round 6: KT=64, single-buffered phase-interleave
// 8 waves (2/SIMD), QB=128, 2-way KV split. Per 64-key tile:
//   V(t) staged during QK(t)  (V unused in QK);  drained at P-barrier.
//   K(t+1) staged during PV(t) (K unused in PV); drained at tile-end barrier.
// 2 barriers per 64 keys (was per 32). K chunk P=ccol*64+key; V chunk P=c*512+ch
// (both conflict-free via chunk-transposed global source). P [128][72] rows.
#define KT 64
#define NTILES 32
__global__ __launch_bounds__(512, 2) void k_attn(
        const short* __restrict__ qT, const short* __restrict__ kT,
        const short* __restrict__ vg, short* __restrict__ O0,
        short* __restrict__ O1, float* __restrict__ L0, float* __restrict__ L1)
{
    __shared__ __align__(16) short pool[74752];
    short* Kp = pool;            // 64KB, chunk P = ccol*64 + key
    short* Vp = pool + 32768;    // 64KB, chunk P = c*512 + ch (c = key-octet)
    short* Pp = pool + 65536;    // 128 x 72 shorts (144B rows)

    int bid0 = blockIdx.x;
    int bid = (bid0 & 7) * 32 + (bid0 >> 3);   // XCD swizzle
    int qt = bid & 31, ks = (bid >> 5) & 1, b = bid >> 6;
    int m0 = qt * 128;
    int t = threadIdx.x, lane = t & 63, w = t >> 6;
    int g = lane >> 4, li = lane & 15;
    int l31 = lane & 31, l5 = lane >> 5;

    const short* kb = kT + (size_t)b * HW * C_DIM + (size_t)ks * 2048 * C_DIM;
    const short* vb = vg + (size_t)b * C_DIM * HW + ks * 2048;

    // Q fragments (16 q rows per wave, 64 VGPR)
    bf16x8 qf[16];
    {
        const short* qrow = qT + ((size_t)b * HW + m0 + w * 16 + li) * C_DIM;
        #pragma unroll
        for (int kc = 0; kc < 16; ++kc)
            qf[kc] = *(const bf16x8*)&qrow[kc * 32 + g * 8];
    }
    f32x16 oacc[8];
    #pragma unroll
    for (int a = 0; a < 8; ++a) oacc[a] = zero16();
    float lsum = 0.f;

    // staging sources (chunk-transpose permutation applied on the global side)
    const short* ksrc = kb + (size_t)(t & 63) * 512 + (t >> 6) * 8;
    const short* vsrc = vb + (size_t)t * 4096;

    const float SC = 0.044194173824159216f * 1.4426950408889634f; // 512^-0.5 * log2(e)

    auto KSTAGE = [&](int nt) {
        const short* kS = ksrc + (size_t)(nt * KT) * 512;
        short* kD = Kp + t * 8;
        #pragma unroll
        for (int r = 0; r < 8; ++r)
            gload16(kS + r * 64, kD + r * 4096);
    };
    auto VSTAGE = [&](int nt) {
        int n0 = nt * KT;
        short* vD = Vp + t * 8;
        #pragma unroll
        for (int r = 0; r < 8; ++r)
            gload16(vsrc + n0 + r * 8, vD + r * 4096);
    };

    // prologue: K(0)
    KSTAGE(0);
    asm volatile("s_waitcnt vmcnt(0)" ::: "memory");
    __builtin_amdgcn_s_barrier();
    __builtin_amdgcn_sched_barrier(0);

    const short* kbase  = Kp + g * 512 + li * 8;
    const short* vbase2 = Vp + l5 * 4096 + (w * 64 + l31) * 8;
    const short* pbase  = Pp + l31 * 72 + l5 * 8;

    for (int nt = 0; nt < NTILES; ++nt) {
        VSTAGE(nt);                     // V(t): drains at P-barrier, used in PV(t)

        // ---- QK (16x16, swapped: mfma(K, Q)); 64 MFMA, 8 chains ----
        f32x4 s[8];
        #pragma unroll
        for (int i = 0; i < 8; ++i) s[i] = zero4();
        __builtin_amdgcn_s_setprio(1);
        #pragma unroll
        for (int kc = 0; kc < 16; kc += 2) {
            #pragma unroll
            for (int fn = 0; fn < 4; ++fn) {
                bf16x8 ka  = *(const bf16x8*)&kbase[kc * 2048 + fn * 128];
                bf16x8 ka2 = *(const bf16x8*)&kbase[(kc + 1) * 2048 + fn * 128];
                s[fn]     = __builtin_amdgcn_mfma_f32_16x16x32_bf16(ka,  qf[kc],     s[fn],     0, 0, 0);
                s[4 + fn] = __builtin_amdgcn_mfma_f32_16x16x32_bf16(ka2, qf[kc + 1], s[4 + fn], 0, 0, 0);
            }
        }
        __builtin_amdgcn_s_setprio(0);

        // softmax (no-max) + P write: P[q = w*16+li][key = fn*16 + g*4 + i]
        #pragma unroll
        for (int fn = 0; fn < 4; ++fn) {
            float e0 = exp2f((s[fn][0] + s[4 + fn][0]) * SC);
            float e1 = exp2f((s[fn][1] + s[4 + fn][1]) * SC);
            float e2 = exp2f((s[fn][2] + s[4 + fn][2]) * SC);
            float e3 = exp2f((s[fn][3] + s[4 + fn][3]) * SC);
            lsum += (e0 + e1) + (e2 + e3);
            union { __hip_bfloat162 h; unsigned u; } p01, p23;
            p01.h = __float22bfloat162_rn(make_float2(e0, e1));
            p23.h = __float22bfloat162_rn(make_float2(e2, e3));
            *(uint2*)&Pp[(w * 16 + li) * 72 + fn * 16 + g * 4] = make_uint2(p01.u, p23.u);
        }

        // P-barrier: P visible to all; V(t) loads drained; all waves done with Kp
        asm volatile("s_waitcnt vmcnt(0) lgkmcnt(0)" ::: "memory");
        __builtin_amdgcn_s_barrier();
        __builtin_amdgcn_sched_barrier(0);

        if (nt + 1 < NTILES) KSTAGE(nt + 1);   // K(t+1): drains at tile-end barrier

        // ---- PV (32x32x16): C[ch][q] += V[ch][k] * P[q][k]; 32 MFMA ----
        __builtin_amdgcn_s_setprio(1);
        #pragma unroll
        for (int kx = 0; kx < 4; ++kx) {
            bf16x8 vf0 = *(const bf16x8*)&vbase2[kx * 8192];
            bf16x8 vf1 = *(const bf16x8*)&vbase2[kx * 8192 + 256];
            #pragma unroll
            for (int q2 = 0; q2 < 4; ++q2) {
                bf16x8 pf = *(const bf16x8*)&pbase[q2 * 2304 + kx * 16];
                oacc[q2 * 2 + 0] = __builtin_amdgcn_mfma_f32_32x32x16_bf16(vf0, pf, oacc[q2 * 2 + 0], 0, 0, 0);
                oacc[q2 * 2 + 1] = __builtin_amdgcn_mfma_f32_32x32x16_bf16(vf1, pf, oacc[q2 * 2 + 1], 0, 0, 0);
            }
        }
        __builtin_amdgcn_s_setprio(0);

        // tile-end barrier: K(t+1) drained; Vp/Pp consumed by all waves
        asm volatile("s_waitcnt vmcnt(0)" ::: "memory");
        __builtin_amdgcn_s_barrier();
        __builtin_amdgcn_sched_barrier(0);
    }

    // row-sum partials (wave w owns queries w*16..w*16+15; query = li)
    lsum += __shfl_xor(lsum, 16);
    lsum += __shfl_xor(lsum, 32);
    float* Lb = (ks ? L1 : L0) + (size_t)b * HW + m0 + w * 16;
    if (lane < 16) Lb[lane] = lsum;

    // O epilogue: per-wave LDS transpose (144B rows) -> coalesced [b][m][c]
    short* tp = pool + w * 9216;
    #pragma unroll
    for (int a = 0; a < 8; ++a) {
        int q2 = a >> 1, cht = a & 1;
        int q_l = q2 * 32 + l31;
        #pragma unroll
        for (int rq = 0; rq < 4; ++rq) {
            int chb = cht * 32 + rq * 8 + l5 * 4;
            union { __hip_bfloat162 h; unsigned u; } x01, x23;
            x01.h = __float22bfloat162_rn(make_float2(oacc[a][rq * 4 + 0], oacc[a][rq * 4 + 1]));
            x23.h = __float22bfloat162_rn(make_float2(oacc[a][rq * 4 + 2], oacc[a][rq * 4 + 3]));
            *(uint2*)&tp[q_l * 72 + chb] = make_uint2(x01.u, x23.u);
        }
    }
    asm volatile("s_waitcnt lgkmcnt(0)" ::: "memory");
    __builtin_amdgcn_sched_barrier(0);
    short* Ob = (ks ? O1 : O0) + ((size_t)b * HW + m0) * C_DIM + w * 64;
    #pragma unroll
    for (int qg = 0; qg < 16; ++qg) {
        int qr = qg * 8 + (lane >> 3);
        bf16x8 v = *(const bf16x8*)&tp[qr * 72 + (lane & 7) * 8];
        *(bf16x8*)&Ob[(size_t)qr * C_DIM + (lane & 7) * 8] = v;
    }
}

__global__ void k_att_comb(const short* __restrict__ O0, const short* __restrict__ O1,
                           const float* __restrict__ L0, const float* __restrict__ L1,
                           short* __restrict__ oatt) {
    int i = blockIdx.x * 256 + threadIdx.x;
    int row = i >> 6;
    int c0 = (i & 63) * 8;
    float r = 1.0f / (L0[row] + L1[row]);
    size_t base = (size_t)row * C_DIM + c0;
    bf16x8 a = *(const bf16x8*)&O0[base];
    bf16x8 c = *(const bf16x8*)&O1[base];
    bf16x8 o;
    #pragma unroll
    for (int j = 0; j < 8; ++j)
        o[j] = f2b((b2f(a[j]) + b2f(c[j])) * r);
    *(bf16x8*)&oatt[base] = o;
}

// ---------------- launch ----------------
extern "C" void kernel_launch(void* const* d_in, const int* in_sizes, int n_in,
                              void* d_out, int out_size, void* d_ws, size_t ws_size,
                              hipStream_t stream) {
    const float* x    = (const float*)d_in[0];
    const float* ln_w = (const float*)d_in[1];
    const float* ln_b = (const float*)d_in[2];
    const float* wq   = (const float*)d_in[3];
    const float* wk   = (const float*)d_in[4];
    const float* wv   = (const float*)d_in[5];
    const float* wp   = (const float*)d_in[6];
    const float* bp   = (const float*)d_in[7];
    float* out = (float*)d_out;

    char* ws = (char*)d_ws;
    size_t off = 0;
    auto alloc = [&](size_t bytes) {
        char* p = ws + off;
        off += (bytes + 255) & ~(size_t)255;
        return p;
    };
    short* hp   = (short*)alloc((size_t)BATCH * PPIX * C_DIM * 2);   // also O-partial 0
    short* wqb  = (short*)alloc((size_t)512 * 512 * 2);
    short* wkr  = (short*)alloc((size_t)512 * 4608 * 2);
    short* wvr  = (short*)alloc((size_t)512 * 4608 * 2);
    short* wpb  = (short*)alloc((size_t)512 * 512 * 2);
    short* qT   = (short*)alloc((size_t)BATCH * HW * C_DIM * 2);
    short* kT   = (short*)alloc((size_t)BATCH * HW * C_DIM * 2);
    short* vg   = (short*)alloc((size_t)BATCH * HW * C_DIM * 2);
    short* oatt = (short*)alloc((size_t)BATCH * HW * C_DIM * 2);     // also O-partial 1
    float* mean = (float*)alloc((size_t)BATCH * HW * 4);             // also Lsum 0
    float* rstd = (float*)alloc((size_t)BATCH * HW * 4);             // also Lsum 1

    hipMemsetAsync(hp, 0, (size_t)BATCH * PPIX * C_DIM * 2, stream);
    k_cvt_bf16<<<1024, 256, 0, stream>>>(wq, wqb, 512 * 512);
    k_cvt_bf16<<<1024, 256, 0, stream>>>(wp, wpb, 512 * 512);
    k_reorder_w3<<<9216, 256, 0, stream>>>(wk, wkr);
    k_reorder_w3<<<9216, 256, 0, stream>>>(wv, wvr);
    k_ln_stats<<<512, 256, 0, stream>>>(x, mean, rstd);
    k_ln_apply<<<2048, 256, 0, stream>>>(x, mean, rstd, ln_w, ln_b, hp);

    k_gemm<1, 0, 0><<<512, 256, 0, stream>>>(hp, wqb, qT, nullptr, nullptr);
    k_gemm_kv<<<512, 256, 0, stream>>>(hp, wkr, wvr, kT, vg);

    short* Op0 = hp;
    short* Op1 = oatt;
    float* Ls0 = mean;
    float* Ls1 = rstd;
    k_attn<<<256, 512, 0, stream>>>(qT, kT, vg, Op0, Op1, Ls0, Ls1);
    k_att_comb<<<4096, 256, 0, stream>>>(Op0, Op1, Ls0, Ls1, oatt);

    k_gemm<1, 1, 2><<<512, 256, 0, stream>>>(oatt, wpb, out, bp, x);
}

// Round 7
// 397.250 us; speedup vs baseline: 1.1325x; 1.1325x over previous
//
#include <hip/hip_runtime.h>
#include <hip/hip_bf16.h>

#define C_DIM 512
#define HW    4096
#define BATCH 4
#define PW    66
#define PPIX  (PW*PW)   // 4356

typedef __attribute__((ext_vector_type(8))) short bf16x8;
typedef __attribute__((ext_vector_type(4))) float f32x4;
typedef __attribute__((ext_vector_type(16))) float f32x16;

static __device__ __forceinline__ short f2b(float f) {
    union { float f; unsigned u; } v; v.f = f;
    unsigned r = v.u + 0x7fffu + ((v.u >> 16) & 1u);
    return (short)(r >> 16);
}
static __device__ __forceinline__ float b2f(short s) {
    union { unsigned u; float f; } v; v.u = ((unsigned)(unsigned short)s) << 16;
    return v.f;
}

static __device__ __forceinline__ f32x4 zero4() {
    f32x4 v = {0.f, 0.f, 0.f, 0.f};
    return v;
}
static __device__ __forceinline__ f32x16 zero16() {
    f32x16 v = {0.f,0.f,0.f,0.f, 0.f,0.f,0.f,0.f, 0.f,0.f,0.f,0.f, 0.f,0.f,0.f,0.f};
    return v;
}

static __device__ __forceinline__ void gload16(const void* g, void* l) {
    __builtin_amdgcn_global_load_lds(
        (__attribute__((address_space(1))) void*)g,
        (__attribute__((address_space(3))) void*)l, 16, 0, 0);
}

// ---------------- weight prep ----------------
__global__ void k_cvt_bf16(const float* __restrict__ in, short* __restrict__ out, int n) {
    int i = blockIdx.x * 256 + threadIdx.x;
    if (i < n) out[i] = f2b(in[i]);
}

__global__ void k_reorder_w3(const float* __restrict__ w, short* __restrict__ out) {
    int i = blockIdx.x * 256 + threadIdx.x;
    int c   = i & 511;
    int tap = (i >> 9) % 9;
    int o   = i / (9 * 512);
    out[i] = f2b(w[((size_t)o * 512 + c) * 9 + tap]);
}

// ---------------- layernorm ----------------
__global__ void k_ln_stats(const float* __restrict__ x, float* __restrict__ mean,
                           float* __restrict__ rstd) {
    __shared__ float ss[8][32];
    __shared__ float sq2[8][32];
    int bid = blockIdx.x;
    int t = threadIdx.x;
    int px = t & 31, cg = t >> 5;
    int p = bid * 32 + px;
    int b = p >> 12, pix = p & 4095;
    const float* xp = x + (size_t)b * C_DIM * HW + pix;
    float s = 0.f, sq = 0.f;
    #pragma unroll 4
    for (int c = cg * 64; c < cg * 64 + 64; ++c) {
        float v = xp[(size_t)c * HW];
        s += v; sq += v * v;
    }
    ss[cg][px] = s;
    sq2[cg][px] = sq;
    __syncthreads();
    if (t < 32) {
        float S = 0.f, Q = 0.f;
        #pragma unroll
        for (int j = 0; j < 8; ++j) { S += ss[j][t]; Q += sq2[j][t]; }
        float mu  = S * (1.0f / C_DIM);
        float var = Q * (1.0f / C_DIM) - mu * mu;
        int pg = bid * 32 + t;
        mean[pg] = mu;
        rstd[pg] = 1.0f / sqrtf(var + 1e-6f);
    }
}

__global__ void k_ln_apply(const float* __restrict__ x, const float* __restrict__ mean,
                           const float* __restrict__ rstd, const float* __restrict__ lnw,
                           const float* __restrict__ lnb, short* __restrict__ hp) {
    __shared__ short tile[64][65];
    int bid = blockIdx.x;
    int ct = bid & 7, y = (bid >> 3) & 63, b = bid >> 9;
    int c0 = ct * 64, p0 = y * 64;
    int t = threadIdx.x;
    int pi = t & 63, ci0 = t >> 6;
    int pg = (b << 12) + p0 + pi;
    float mu = mean[pg], rs = rstd[pg];
    const float* xb = x + (size_t)b * C_DIM * HW;
    #pragma unroll
    for (int cc = 0; cc < 64; cc += 4) {
        int c = c0 + cc + ci0;
        float v = xb[(size_t)c * HW + p0 + pi];
        tile[cc + ci0][pi] = f2b((v - mu) * rs * lnw[c] + lnb[c]);
    }
    __syncthreads();
    int cj = t & 63, pj = t >> 6;
    #pragma unroll
    for (int pp = 0; pp < 64; pp += 4) {
        int pidx = pp + pj;
        size_t dst = ((size_t)b * PPIX + (size_t)(y + 1) * PW + 1 + pidx) * C_DIM + c0 + cj;
        hp[dst] = tile[cj][pidx];
    }
}

// ---------------- conv-as-GEMM (q and proj) ----------------
template<int TAPS, int GMODE, int EPI>
__global__ __launch_bounds__(256, 2) void k_gemm(
        const short* __restrict__ A, const short* __restrict__ Bw,
        void* __restrict__ Out, const float* __restrict__ bias,
        const float* __restrict__ resid)
{
    constexpr int K = TAPS * 512;
    constexpr int NKC = K / 64;
    __shared__ short Alds[128 * 64];
    __shared__ short Blds[128 * 64];
    int bid = blockIdx.x;
    int mt = bid & 31, nt = (bid >> 5) & 3, b = bid >> 7;
    int m0 = mt * 128, n0 = nt * 128;
    int t = threadIdx.x;
    int lane = t & 63, w = t >> 6;
    int wm = w >> 1, wn = w & 1;
    int g = lane >> 4, li = lane & 15;
    int srow = t >> 3, schunk = t & 7;
    const short* Ab = A + (GMODE == 0 ? (size_t)b * PPIX * C_DIM : (size_t)b * HW * C_DIM);

    f32x4 acc[4][4];
    #pragma unroll
    for (int i = 0; i < 4; ++i)
        #pragma unroll
        for (int j = 0; j < 4; ++j) acc[i][j] = zero4();

    for (int kc = 0; kc < NKC; ++kc) {
        int tap = (TAPS == 9) ? (kc >> 3) : 4;
        int cb  = (kc & 7) * 64;
        __syncthreads();
        #pragma unroll
        for (int r = 0; r < 4; ++r) {
            int row = r * 32 + srow;
            size_t goff;
            if (GMODE == 0) {
                int m = m0 + row;
                int yy = m >> 6, xx = m & 63;
                int pp = (yy + tap / 3) * PW + xx + (tap % 3);
                goff = (size_t)pp * C_DIM + cb + schunk * 8;
            } else {
                goff = (size_t)(m0 + row) * K + kc * 64 + schunk * 8;
            }
            gload16(Ab + goff, Alds + row * 64 + schunk * 8);
        }
        #pragma unroll
        for (int r = 0; r < 4; ++r) {
            int row = r * 32 + srow;
            size_t goff = (size_t)(n0 + row) * K + kc * 64 + schunk * 8;
            gload16(Bw + goff, Blds + row * 64 + schunk * 8);
        }
        __syncthreads();
        #pragma unroll
        for (int ks = 0; ks < 2; ++ks) {
            int koff = ks * 32 + g * 8;
            bf16x8 af[4], bfr[4];
            #pragma unroll
            for (int i = 0; i < 4; ++i)
                af[i] = *(const bf16x8*)&Alds[(wm * 64 + i * 16 + li) * 64 + koff];
            #pragma unroll
            for (int j = 0; j < 4; ++j)
                bfr[j] = *(const bf16x8*)&Blds[(wn * 64 + j * 16 + li) * 64 + koff];
            #pragma unroll
            for (int i = 0; i < 4; ++i)
                #pragma unroll
                for (int j = 0; j < 4; ++j)
                    acc[i][j] = __builtin_amdgcn_mfma_f32_16x16x32_bf16(af[i], bfr[j], acc[i][j], 0, 0, 0);
        }
    }
    #pragma unroll
    for (int fm = 0; fm < 4; ++fm) {
        #pragma unroll
        for (int fn = 0; fn < 4; ++fn) {
            int mrow = m0 + wm * 64 + fm * 16 + g * 4;
            int ncol = n0 + wn * 64 + fn * 16 + li;
            if constexpr (EPI == 0) {
                #pragma unroll
                for (int i = 0; i < 4; ++i) {
                    size_t dst = ((size_t)b * HW + mrow + i) * C_DIM + ncol;
                    ((short*)Out)[dst] = f2b(acc[fm][fn][i]);
                }
            } else if constexpr (EPI == 1) {
                size_t dst = ((size_t)b * C_DIM + ncol) * HW + mrow;
                short4 sv = make_short4(f2b(acc[fm][fn][0]), f2b(acc[fm][fn][1]),
                                        f2b(acc[fm][fn][2]), f2b(acc[fm][fn][3]));
                *(short4*)((short*)Out + dst) = sv;
            } else {
                size_t dst = ((size_t)b * C_DIM + ncol) * HW + mrow;
                float bb = bias[ncol];
                float4 xr = *(const float4*)(resid + dst);
                float4 o;
                o.x = acc[fm][fn][0] + bb + xr.x;
                o.y = acc[fm][fn][1] + bb + xr.y;
                o.z = acc[fm][fn][2] + bb + xr.z;
                o.w = acc[fm][fn][3] + bb + xr.w;
                *(float4*)((float*)Out + dst) = o;
            }
        }
    }
}

// ---------------- fused K+V 3x3 conv ----------------
__global__ __launch_bounds__(256, 2) void k_gemm_kv(
        const short* __restrict__ A, const short* __restrict__ Bk,
        const short* __restrict__ Bv, short* __restrict__ OutK,
        short* __restrict__ OutV)
{
    constexpr int K = 4608;
    __shared__ short Alds[128 * 64];
    __shared__ short Bklds[128 * 64];
    __shared__ short Bvlds[128 * 64];
    int bid = blockIdx.x;
    int mt = bid & 31, nt = (bid >> 5) & 3, b = bid >> 7;
    int m0 = mt * 128, n0 = nt * 128;
    int t = threadIdx.x;
    int lane = t & 63, w = t >> 6;
    int wm = w >> 1, wn = w & 1;
    int g = lane >> 4, li = lane & 15;
    int srow = t >> 3, schunk = t & 7;
    const short* Ab = A + (size_t)b * PPIX * C_DIM;

    f32x4 accK[4][4], accV[4][4];
    #pragma unroll
    for (int i = 0; i < 4; ++i)
        #pragma unroll
        for (int j = 0; j < 4; ++j) { accK[i][j] = zero4(); accV[i][j] = zero4(); }

    for (int kc = 0; kc < 72; ++kc) {
        int tap = kc >> 3;
        int cb  = (kc & 7) * 64;
        __syncthreads();
        #pragma unroll
        for (int r = 0; r < 4; ++r) {
            int row = r * 32 + srow;
            int m = m0 + row;
            int yy = m >> 6, xx = m & 63;
            int pp = (yy + tap / 3) * PW + xx + (tap % 3);
            gload16(Ab + (size_t)pp * C_DIM + cb + schunk * 8, Alds + row * 64 + schunk * 8);
        }
        #pragma unroll
        for (int r = 0; r < 4; ++r) {
            int row = r * 32 + srow;
            size_t goff = (size_t)(n0 + row) * K + kc * 64 + schunk * 8;
            gload16(Bk + goff, Bklds + row * 64 + schunk * 8);
            gload16(Bv + goff, Bvlds + row * 64 + schunk * 8);
        }
        __syncthreads();
        #pragma unroll
        for (int ks = 0; ks < 2; ++ks) {
            int koff = ks * 32 + g * 8;
            bf16x8 af[4], bk[4], bv[4];
            #pragma unroll
            for (int i = 0; i < 4; ++i)
                af[i] = *(const bf16x8*)&Alds[(wm * 64 + i * 16 + li) * 64 + koff];
            #pragma unroll
            for (int j = 0; j < 4; ++j)
                bk[j] = *(const bf16x8*)&Bklds[(wn * 64 + j * 16 + li) * 64 + koff];
            #pragma unroll
            for (int i = 0; i < 4; ++i)
                #pragma unroll
                for (int j = 0; j < 4; ++j)
                    accK[i][j] = __builtin_amdgcn_mfma_f32_16x16x32_bf16(af[i], bk[j], accK[i][j], 0, 0, 0);
            #pragma unroll
            for (int j = 0; j < 4; ++j)
                bv[j] = *(const bf16x8*)&Bvlds[(wn * 64 + j * 16 + li) * 64 + koff];
            #pragma unroll
            for (int i = 0; i < 4; ++i)
                #pragma unroll
                for (int j = 0; j < 4; ++j)
                    accV[i][j] = __builtin_amdgcn_mfma_f32_16x16x32_bf16(af[i], bv[j], accV[i][j], 0, 0, 0);
        }
    }
    #pragma unroll
    for (int fm = 0; fm < 4; ++fm) {
        #pragma unroll
        for (int fn = 0; fn < 4; ++fn) {
            int mrow = m0 + wm * 64 + fm * 16 + g * 4;
            int ncol = n0 + wn * 64 + fn * 16 + li;
            #pragma unroll
            for (int i = 0; i < 4; ++i) {
                size_t dst = ((size_t)b * HW + mrow + i) * C_DIM + ncol;
                OutK[dst] = f2b(accK[fm][fn][i]);
            }
            size_t dstv = ((size_t)b * C_DIM + ncol) * HW + mrow;
            short4 sv = make_short4(f2b(accV[fm][fn][0]), f2b(accV[fm][fn][1]),
                                    f2b(accV[fm][fn][2]), f2b(accV[fm][fn][3]));
            *(short4*)(OutV + dstv) = sv;
        }
    }
}

// ---------------- flash attention, round 7: r5 structure + split waits ----------
// Double-buffered KT=32, 8 waves. Mid-tile P-barrier waits lgkmcnt ONLY (P is an
// LDS condition; V(t)/K(t) drained at previous tile-end). Tile-end barrier waits
// vmcnt(0) for the prefetch STAGE(t+1) -> full tile of compute covers its latency.
#define KT 32
#define NTILES 64
__global__ __launch_bounds__(512, 2) void k_attn(
        const short* __restrict__ qT, const short* __restrict__ kT,
        const short* __restrict__ vg, short* __restrict__ O0,
        short* __restrict__ O1, float* __restrict__ L0, float* __restrict__ L1)
{
    __shared__ __align__(16) short pool[78848];
    short* Kp = pool;               // 2 x 16384 shorts (K: chunk P=ccol*32+key)
    short* Vp = pool + 32768;       // 2 x 20480 shorts (V: [ch][40] rows)
    short* Pp = pool + 73728;       // 128 x 40 shorts  (P: 80B rows)

    int bid0 = blockIdx.x;
    int bid = (bid0 & 7) * 32 + (bid0 >> 3);   // XCD swizzle: one (ks,b) pair per XCD
    int qt = bid & 31, ks = (bid >> 5) & 1, b = bid >> 6;
    int m0 = qt * 128;
    int t = threadIdx.x, lane = t & 63, w = t >> 6;
    int g = lane >> 4, li = lane & 15;
    int l31 = lane & 31, l5 = lane >> 5;

    const short* kb = kT + (size_t)b * HW * C_DIM + (size_t)ks * 2048 * C_DIM;
    const short* vb = vg + (size_t)b * C_DIM * HW + ks * 2048;

    // Q fragments (16 q rows per wave, 64 VGPR)
    bf16x8 qf[16];
    {
        const short* qrow = qT + ((size_t)b * HW + m0 + w * 16 + li) * C_DIM;
        #pragma unroll
        for (int kc = 0; kc < 16; ++kc)
            qf[kc] = *(const bf16x8*)&qrow[kc * 32 + g * 8];
    }
    f32x16 oacc[8];
    #pragma unroll
    for (int a = 0; a < 8; ++a) oacc[a] = zero16();
    float lsum = 0.f;

    // K staging source (chunk-transposed)
    const short* ksrc = kb + (size_t)(t & 31) * 512 + (t >> 5) * 8;
    // V staging: dest chunk D = r*512+t -> (ch=D/5, c=D%5); c==4 is pad
    int voff[5];
    #pragma unroll
    for (int r = 0; r < 5; ++r) {
        int D = r * 512 + t;
        int ch = D / 5;
        int c  = D - ch * 5;
        voff[r] = (c < 4) ? ch * 4096 + c * 8 : 0;
    }

    const float SC = 0.044194173824159216f * 1.4426950408889634f; // 512^-0.5 * log2(e)

    auto STAGE = [&](int buf, int nt) {
        int n0 = nt * KT;
        const short* kS = ksrc + (size_t)n0 * 512;
        short* kD = Kp + buf * 16384 + t * 8;
        #pragma unroll
        for (int r = 0; r < 4; ++r)
            gload16(kS + r * 128, kD + r * 4096);
        short* vD = Vp + buf * 20480 + t * 8;
        #pragma unroll
        for (int r = 0; r < 5; ++r)
            gload16(vb + voff[r] + n0, vD + r * 4096);
    };

    STAGE(0, 0);
    asm volatile("s_waitcnt vmcnt(0)" ::: "memory");
    __builtin_amdgcn_s_barrier();
    __builtin_amdgcn_sched_barrier(0);

    int buf = 0;
    for (int nt = 0; nt < NTILES; ++nt) {
        if (nt + 1 < NTILES) STAGE(buf ^ 1, nt + 1);   // prefetch: drains at tile-end

        // ---- QK (16x16, swapped: mfma(K, Q)) ----
        const short* kbase = Kp + buf * 16384 + g * 256 + li * 8;
        f32x4 s0[2], s1[2];
        s0[0] = zero4(); s0[1] = zero4(); s1[0] = zero4(); s1[1] = zero4();
        __builtin_amdgcn_s_setprio(1);
        #pragma unroll
        for (int kc = 0; kc < 16; kc += 2) {
            #pragma unroll
            for (int fn = 0; fn < 2; ++fn) {
                bf16x8 ka  = *(const bf16x8*)&kbase[kc * 1024 + fn * 128];
                bf16x8 ka2 = *(const bf16x8*)&kbase[(kc + 1) * 1024 + fn * 128];
                s0[fn] = __builtin_amdgcn_mfma_f32_16x16x32_bf16(ka,  qf[kc],     s0[fn], 0, 0, 0);
                s1[fn] = __builtin_amdgcn_mfma_f32_16x16x32_bf16(ka2, qf[kc + 1], s1[fn], 0, 0, 0);
            }
        }
        __builtin_amdgcn_s_setprio(0);
        // softmax (no-max) + P write: P[q = w*16+li][key = fn*16+g*4+i]
        #pragma unroll
        for (int fn = 0; fn < 2; ++fn) {
            float e0 = exp2f((s0[fn][0] + s1[fn][0]) * SC);
            float e1 = exp2f((s0[fn][1] + s1[fn][1]) * SC);
            float e2 = exp2f((s0[fn][2] + s1[fn][2]) * SC);
            float e3 = exp2f((s0[fn][3] + s1[fn][3]) * SC);
            lsum += (e0 + e1) + (e2 + e3);
            union { __hip_bfloat162 h; unsigned u; } p01, p23;
            p01.h = __float22bfloat162_rn(make_float2(e0, e1));
            p23.h = __float22bfloat162_rn(make_float2(e2, e3));
            *(uint2*)&Pp[(w * 16 + li) * 40 + fn * 16 + g * 4] = make_uint2(p01.u, p23.u);
        }

        // mid-tile barrier: P visible. LDS-only wait; prefetch stays in flight.
        asm volatile("s_waitcnt lgkmcnt(0)" ::: "memory");
        __builtin_amdgcn_s_barrier();
        __builtin_amdgcn_sched_barrier(0);

        // ---- PV (32x32x16): C[ch][q] += V[ch][k] * P[q][k] ----
        const short* vbase = Vp + buf * 20480 + (size_t)w * 64 * 40;
        bf16x8 vf[2][2];
        #pragma unroll
        for (int cht = 0; cht < 2; ++cht)
            #pragma unroll
            for (int kx = 0; kx < 2; ++kx)
                vf[cht][kx] = *(const bf16x8*)&vbase[(cht * 32 + l31) * 40 + kx * 16 + l5 * 8];
        __builtin_amdgcn_s_setprio(1);
        #pragma unroll
        for (int q2 = 0; q2 < 4; ++q2) {
            #pragma unroll
            for (int kx = 0; kx < 2; ++kx) {
                bf16x8 pf = *(const bf16x8*)&Pp[(q2 * 32 + l31) * 40 + kx * 16 + l5 * 8];
                oacc[q2 * 2 + 0] = __builtin_amdgcn_mfma_f32_32x32x16_bf16(vf[0][kx], pf, oacc[q2 * 2 + 0], 0, 0, 0);
                oacc[q2 * 2 + 1] = __builtin_amdgcn_mfma_f32_32x32x16_bf16(vf[1][kx], pf, oacc[q2 * 2 + 1], 0, 0, 0);
            }
        }
        __builtin_amdgcn_s_setprio(0);

        // tile-end barrier: prefetch STAGE(t+1) drained; Pp consumed by all waves.
        asm volatile("s_waitcnt vmcnt(0)" ::: "memory");
        __builtin_amdgcn_s_barrier();
        __builtin_amdgcn_sched_barrier(0);
        buf ^= 1;
    }

    // row-sum partials (wave w owns queries w*16..w*16+15; query = li)
    lsum += __shfl_xor(lsum, 16);
    lsum += __shfl_xor(lsum, 32);
    float* Lb = (ks ? L1 : L0) + (size_t)b * HW + m0 + w * 16;
    if (lane < 16) Lb[lane] = lsum;

    // O epilogue: per-wave LDS transpose (144B rows) -> coalesced [b][m][c]
    short* tp = pool + w * 9216;
    #pragma unroll
    for (int a = 0; a < 8; ++a) {
        int q2 = a >> 1, cht = a & 1;
        int q_l = q2 * 32 + l31;
        #pragma unroll
        for (int rq = 0; rq < 4; ++rq) {
            int chb = cht * 32 + rq * 8 + l5 * 4;
            union { __hip_bfloat162 h; unsigned u; } x01, x23;
            x01.h = __float22bfloat162_rn(make_float2(oacc[a][rq * 4 + 0], oacc[a][rq * 4 + 1]));
            x23.h = __float22bfloat162_rn(make_float2(oacc[a][rq * 4 + 2], oacc[a][rq * 4 + 3]));
            *(uint2*)&tp[q_l * 72 + chb] = make_uint2(x01.u, x23.u);
        }
    }
    asm volatile("s_waitcnt lgkmcnt(0)" ::: "memory");
    __builtin_amdgcn_sched_barrier(0);
    short* Ob = (ks ? O1 : O0) + ((size_t)b * HW + m0) * C_DIM + w * 64;
    #pragma unroll
    for (int qg = 0; qg < 16; ++qg) {
        int qr = qg * 8 + (lane >> 3);
        bf16x8 v = *(const bf16x8*)&tp[qr * 72 + (lane & 7) * 8];
        *(bf16x8*)&Ob[(size_t)qr * C_DIM + (lane & 7) * 8] = v;
    }
}

__global__ void k_att_comb(const short* __restrict__ O0, const short* __restrict__ O1,
                           const float* __restrict__ L0, const float* __restrict__ L1,
                           short* __restrict__ oatt) {
    int i = blockIdx.x * 256 + threadIdx.x;
    int row = i >> 6;
    int c0 = (i & 63) * 8;
    float r = 1.0f / (L0[row] + L1[row]);
    size_t base = (size_t)row * C_DIM + c0;
    bf16x8 a = *(const bf16x8*)&O0[base];
    bf16x8 c = *(const bf16x8*)&O1[base];
    bf16x8 o;
    #pragma unroll
    for (int j = 0; j < 8; ++j)
        o[j] = f2b((b2f(a[j]) + b2f(c[j])) * r);
    *(bf16x8*)&oatt[base] = o;
}

// ---------------- launch ----------------
extern "C" void kernel_launch(void* const* d_in, const int* in_sizes, int n_in,
                              void* d_out, int out_size, void* d_ws, size_t ws_size,
                              hipStream_t stream) {
    const float* x    = (const float*)d_in[0];
    const float* ln_w = (const float*)d_in[1];
    const float* ln_b = (const float*)d_in[2];
    const float* wq   = (const float*)d_in[3];
    const float* wk   = (const float*)d_in[4];
    const float* wv   = (const float*)d_in[5];
    const float* wp   = (const float*)d_in[6];
    const float* bp   = (const float*)d_in[7];
    float* out = (float*)d_out;

    char* ws = (char*)d_ws;
    size_t off = 0;
    auto alloc = [&](size_t bytes) {
        char* p = ws + off;
        off += (bytes + 255) & ~(size_t)255;
        return p;
    };
    short* hp   = (short*)alloc((size_t)BATCH * PPIX * C_DIM * 2);   // also O-partial 0
    short* wqb  = (short*)alloc((size_t)512 * 512 * 2);
    short* wkr  = (short*)alloc((size_t)512 * 4608 * 2);
    short* wvr  = (short*)alloc((size_t)512 * 4608 * 2);
    short* wpb  = (short*)alloc((size_t)512 * 512 * 2);
    short* qT   = (short*)alloc((size_t)BATCH * HW * C_DIM * 2);
    short* kT   = (short*)alloc((size_t)BATCH * HW * C_DIM * 2);
    short* vg   = (short*)alloc((size_t)BATCH * HW * C_DIM * 2);
    short* oatt = (short*)alloc((size_t)BATCH * HW * C_DIM * 2);     // also O-partial 1
    float* mean = (float*)alloc((size_t)BATCH * HW * 4);             // also Lsum 0
    float* rstd = (float*)alloc((size_t)BATCH * HW * 4);             // also Lsum 1

    hipMemsetAsync(hp, 0, (size_t)BATCH * PPIX * C_DIM * 2, stream);
    k_cvt_bf16<<<1024, 256, 0, stream>>>(wq, wqb, 512 * 512);
    k_cvt_bf16<<<1024, 256, 0, stream>>>(wp, wpb, 512 * 512);
    k_reorder_w3<<<9216, 256, 0, stream>>>(wk, wkr);
    k_reorder_w3<<<9216, 256, 0, stream>>>(wv, wvr);
    k_ln_stats<<<512, 256, 0, stream>>>(x, mean, rstd);
    k_ln_apply<<<2048, 256, 0, stream>>>(x, mean, rstd, ln_w, ln_b, hp);

    k_gemm<1, 0, 0><<<512, 256, 0, stream>>>(hp, wqb, qT, nullptr, nullptr);
    k_gemm_kv<<<512, 256, 0, stream>>>(hp, wkr, wvr, kT, vg);

    short* Op0 = hp;
    short* Op1 = oatt;
    float* Ls0 = mean;
    float* Ls1 = rstd;
    k_attn<<<256, 512, 0, stream>>>(qT, kT, vg, Op0, Op1, Ls0, Ls1);
    k_att_comb<<<4096, 256, 0, stream>>>(Op0, Op1, Ls0, Ls1, oatt);

    k_gemm<1, 1, 2><<<512, 256, 0, stream>>>(oatt, wpb, out, bp, x);
}

// Round 8
// 376.120 us; speedup vs baseline: 1.1961x; 1.0562x over previous
//
#include <hip/hip_runtime.h>
#include <hip/hip_bf16.h>

#define C_DIM 512
#define HW    4096
#define BATCH 4
#define PW    66
#define PPIX  (PW*PW)   // 4356

typedef __attribute__((ext_vector_type(8))) short bf16x8;
typedef __attribute__((ext_vector_type(4))) float f32x4;
typedef __attribute__((ext_vector_type(16))) float f32x16;
typedef __attribute__((ext_vector_type(2))) long long l64x2;

static __device__ __forceinline__ short f2b(float f) {
    union { float f; unsigned u; } v; v.f = f;
    unsigned r = v.u + 0x7fffu + ((v.u >> 16) & 1u);
    return (short)(r >> 16);
}
static __device__ __forceinline__ float b2f(short s) {
    union { unsigned u; float f; } v; v.u = ((unsigned)(unsigned short)s) << 16;
    return v.f;
}

static __device__ __forceinline__ f32x4 zero4() {
    f32x4 v = {0.f, 0.f, 0.f, 0.f};
    return v;
}
static __device__ __forceinline__ f32x16 zero16() {
    f32x16 v = {0.f,0.f,0.f,0.f, 0.f,0.f,0.f,0.f, 0.f,0.f,0.f,0.f, 0.f,0.f,0.f,0.f};
    return v;
}

static __device__ __forceinline__ void gload16(const void* g, void* l) {
    __builtin_amdgcn_global_load_lds(
        (__attribute__((address_space(1))) void*)g,
        (__attribute__((address_space(3))) void*)l, 16, 0, 0);
}

// ---------------- weight prep ----------------
__global__ void k_cvt_bf16(const float* __restrict__ in, short* __restrict__ out, int n) {
    int i = blockIdx.x * 256 + threadIdx.x;
    if (i < n) out[i] = f2b(in[i]);
}

__global__ void k_reorder_w3(const float* __restrict__ w, short* __restrict__ out) {
    int i = blockIdx.x * 256 + threadIdx.x;
    int c   = i & 511;
    int tap = (i >> 9) % 9;
    int o   = i / (9 * 512);
    out[i] = f2b(w[((size_t)o * 512 + c) * 9 + tap]);
}

// K bf16 -> fp8 e4m3, with kc-pair byte permutation:
// out byte p of row m: kcp=p>>6, g=(p>>4)&3, half=(p>>3)&1, j=p&7
//   <- channel (kcp*2+half)*32 + g*8 + j
__global__ void k_cvt_k8(const short* __restrict__ in, unsigned char* __restrict__ out) {
    int i = blockIdx.x * 256 + threadIdx.x;     // 1M threads, 8 bytes each
    int m = i >> 6;
    int p = (i & 63) * 8;
    int kcp = p >> 6, g = (p >> 4) & 3, half = (p >> 3) & 1;
    int chb = (kcp * 2 + half) * 32 + g * 8;
    bf16x8 v = *(const bf16x8*)&in[(size_t)m * 512 + chb];
    int lo = __builtin_amdgcn_cvt_pk_fp8_f32(b2f(v[0]), b2f(v[1]), 0, false);
    lo     = __builtin_amdgcn_cvt_pk_fp8_f32(b2f(v[2]), b2f(v[3]), lo, true);
    int hi = __builtin_amdgcn_cvt_pk_fp8_f32(b2f(v[4]), b2f(v[5]), 0, false);
    hi     = __builtin_amdgcn_cvt_pk_fp8_f32(b2f(v[6]), b2f(v[7]), hi, true);
    *(uint2*)&out[(size_t)m * 512 + p] = make_uint2((unsigned)lo, (unsigned)hi);
}

// ---------------- layernorm ----------------
__global__ void k_ln_stats(const float* __restrict__ x, float* __restrict__ mean,
                           float* __restrict__ rstd) {
    __shared__ float ss[8][32];
    __shared__ float sq2[8][32];
    int bid = blockIdx.x;
    int t = threadIdx.x;
    int px = t & 31, cg = t >> 5;
    int p = bid * 32 + px;
    int b = p >> 12, pix = p & 4095;
    const float* xp = x + (size_t)b * C_DIM * HW + pix;
    float s = 0.f, sq = 0.f;
    #pragma unroll 4
    for (int c = cg * 64; c < cg * 64 + 64; ++c) {
        float v = xp[(size_t)c * HW];
        s += v; sq += v * v;
    }
    ss[cg][px] = s;
    sq2[cg][px] = sq;
    __syncthreads();
    if (t < 32) {
        float S = 0.f, Q = 0.f;
        #pragma unroll
        for (int j = 0; j < 8; ++j) { S += ss[j][t]; Q += sq2[j][t]; }
        float mu  = S * (1.0f / C_DIM);
        float var = Q * (1.0f / C_DIM) - mu * mu;
        int pg = bid * 32 + t;
        mean[pg] = mu;
        rstd[pg] = 1.0f / sqrtf(var + 1e-6f);
    }
}

__global__ void k_ln_apply(const float* __restrict__ x, const float* __restrict__ mean,
                           const float* __restrict__ rstd, const float* __restrict__ lnw,
                           const float* __restrict__ lnb, short* __restrict__ hp) {
    __shared__ short tile[64][65];
    int bid = blockIdx.x;
    int ct = bid & 7, y = (bid >> 3) & 63, b = bid >> 9;
    int c0 = ct * 64, p0 = y * 64;
    int t = threadIdx.x;
    int pi = t & 63, ci0 = t >> 6;
    int pg = (b << 12) + p0 + pi;
    float mu = mean[pg], rs = rstd[pg];
    const float* xb = x + (size_t)b * C_DIM * HW;
    #pragma unroll
    for (int cc = 0; cc < 64; cc += 4) {
        int c = c0 + cc + ci0;
        float v = xb[(size_t)c * HW + p0 + pi];
        tile[cc + ci0][pi] = f2b((v - mu) * rs * lnw[c] + lnb[c]);
    }
    __syncthreads();
    int cj = t & 63, pj = t >> 6;
    #pragma unroll
    for (int pp = 0; pp < 64; pp += 4) {
        int pidx = pp + pj;
        size_t dst = ((size_t)b * PPIX + (size_t)(y + 1) * PW + 1 + pidx) * C_DIM + c0 + cj;
        hp[dst] = tile[cj][pidx];
    }
}

// ---------------- conv-as-GEMM (q and proj) ----------------
template<int TAPS, int GMODE, int EPI>
__global__ __launch_bounds__(256, 2) void k_gemm(
        const short* __restrict__ A, const short* __restrict__ Bw,
        void* __restrict__ Out, const float* __restrict__ bias,
        const float* __restrict__ resid)
{
    constexpr int K = TAPS * 512;
    constexpr int NKC = K / 64;
    __shared__ short Alds[128 * 64];
    __shared__ short Blds[128 * 64];
    int bid = blockIdx.x;
    int mt = bid & 31, nt = (bid >> 5) & 3, b = bid >> 7;
    int m0 = mt * 128, n0 = nt * 128;
    int t = threadIdx.x;
    int lane = t & 63, w = t >> 6;
    int wm = w >> 1, wn = w & 1;
    int g = lane >> 4, li = lane & 15;
    int srow = t >> 3, schunk = t & 7;
    const short* Ab = A + (GMODE == 0 ? (size_t)b * PPIX * C_DIM : (size_t)b * HW * C_DIM);

    f32x4 acc[4][4];
    #pragma unroll
    for (int i = 0; i < 4; ++i)
        #pragma unroll
        for (int j = 0; j < 4; ++j) acc[i][j] = zero4();

    for (int kc = 0; kc < NKC; ++kc) {
        int tap = (TAPS == 9) ? (kc >> 3) : 4;
        int cb  = (kc & 7) * 64;
        __syncthreads();
        #pragma unroll
        for (int r = 0; r < 4; ++r) {
            int row = r * 32 + srow;
            size_t goff;
            if (GMODE == 0) {
                int m = m0 + row;
                int yy = m >> 6, xx = m & 63;
                int pp = (yy + tap / 3) * PW + xx + (tap % 3);
                goff = (size_t)pp * C_DIM + cb + schunk * 8;
            } else {
                goff = (size_t)(m0 + row) * K + kc * 64 + schunk * 8;
            }
            gload16(Ab + goff, Alds + row * 64 + schunk * 8);
        }
        #pragma unroll
        for (int r = 0; r < 4; ++r) {
            int row = r * 32 + srow;
            size_t goff = (size_t)(n0 + row) * K + kc * 64 + schunk * 8;
            gload16(Bw + goff, Blds + row * 64 + schunk * 8);
        }
        __syncthreads();
        #pragma unroll
        for (int ks = 0; ks < 2; ++ks) {
            int koff = ks * 32 + g * 8;
            bf16x8 af[4], bfr[4];
            #pragma unroll
            for (int i = 0; i < 4; ++i)
                af[i] = *(const bf16x8*)&Alds[(wm * 64 + i * 16 + li) * 64 + koff];
            #pragma unroll
            for (int j = 0; j < 4; ++j)
                bfr[j] = *(const bf16x8*)&Blds[(wn * 64 + j * 16 + li) * 64 + koff];
            #pragma unroll
            for (int i = 0; i < 4; ++i)
                #pragma unroll
                for (int j = 0; j < 4; ++j)
                    acc[i][j] = __builtin_amdgcn_mfma_f32_16x16x32_bf16(af[i], bfr[j], acc[i][j], 0, 0, 0);
        }
    }
    #pragma unroll
    for (int fm = 0; fm < 4; ++fm) {
        #pragma unroll
        for (int fn = 0; fn < 4; ++fn) {
            int mrow = m0 + wm * 64 + fm * 16 + g * 4;
            int ncol = n0 + wn * 64 + fn * 16 + li;
            if constexpr (EPI == 0) {
                #pragma unroll
                for (int i = 0; i < 4; ++i) {
                    size_t dst = ((size_t)b * HW + mrow + i) * C_DIM + ncol;
                    ((short*)Out)[dst] = f2b(acc[fm][fn][i]);
                }
            } else if constexpr (EPI == 1) {
                size_t dst = ((size_t)b * C_DIM + ncol) * HW + mrow;
                short4 sv = make_short4(f2b(acc[fm][fn][0]), f2b(acc[fm][fn][1]),
                                        f2b(acc[fm][fn][2]), f2b(acc[fm][fn][3]));
                *(short4*)((short*)Out + dst) = sv;
            } else {
                size_t dst = ((size_t)b * C_DIM + ncol) * HW + mrow;
                float bb = bias[ncol];
                float4 xr = *(const float4*)(resid + dst);
                float4 o;
                o.x = acc[fm][fn][0] + bb + xr.x;
                o.y = acc[fm][fn][1] + bb + xr.y;
                o.z = acc[fm][fn][2] + bb + xr.z;
                o.w = acc[fm][fn][3] + bb + xr.w;
                *(float4*)((float*)Out + dst) = o;
            }
        }
    }
}

// ---------------- fused K+V 3x3 conv ----------------
__global__ __launch_bounds__(256, 2) void k_gemm_kv(
        const short* __restrict__ A, const short* __restrict__ Bk,
        const short* __restrict__ Bv, short* __restrict__ OutK,
        short* __restrict__ OutV)
{
    constexpr int K = 4608;
    __shared__ short Alds[128 * 64];
    __shared__ short Bklds[128 * 64];
    __shared__ short Bvlds[128 * 64];
    int bid = blockIdx.x;
    int mt = bid & 31, nt = (bid >> 5) & 3, b = bid >> 7;
    int m0 = mt * 128, n0 = nt * 128;
    int t = threadIdx.x;
    int lane = t & 63, w = t >> 6;
    int wm = w >> 1, wn = w & 1;
    int g = lane >> 4, li = lane & 15;
    int srow = t >> 3, schunk = t & 7;
    const short* Ab = A + (size_t)b * PPIX * C_DIM;

    f32x4 accK[4][4], accV[4][4];
    #pragma unroll
    for (int i = 0; i < 4; ++i)
        #pragma unroll
        for (int j = 0; j < 4; ++j) { accK[i][j] = zero4(); accV[i][j] = zero4(); }

    for (int kc = 0; kc < 72; ++kc) {
        int tap = kc >> 3;
        int cb  = (kc & 7) * 64;
        __syncthreads();
        #pragma unroll
        for (int r = 0; r < 4; ++r) {
            int row = r * 32 + srow;
            int m = m0 + row;
            int yy = m >> 6, xx = m & 63;
            int pp = (yy + tap / 3) * PW + xx + (tap % 3);
            gload16(Ab + (size_t)pp * C_DIM + cb + schunk * 8, Alds + row * 64 + schunk * 8);
        }
        #pragma unroll
        for (int r = 0; r < 4; ++r) {
            int row = r * 32 + srow;
            size_t goff = (size_t)(n0 + row) * K + kc * 64 + schunk * 8;
            gload16(Bk + goff, Bklds + row * 64 + schunk * 8);
            gload16(Bv + goff, Bvlds + row * 64 + schunk * 8);
        }
        __syncthreads();
        #pragma unroll
        for (int ks = 0; ks < 2; ++ks) {
            int koff = ks * 32 + g * 8;
            bf16x8 af[4], bk[4], bv[4];
            #pragma unroll
            for (int i = 0; i < 4; ++i)
                af[i] = *(const bf16x8*)&Alds[(wm * 64 + i * 16 + li) * 64 + koff];
            #pragma unroll
            for (int j = 0; j < 4; ++j)
                bk[j] = *(const bf16x8*)&Bklds[(wn * 64 + j * 16 + li) * 64 + koff];
            #pragma unroll
            for (int i = 0; i < 4; ++i)
                #pragma unroll
                for (int j = 0; j < 4; ++j)
                    accK[i][j] = __builtin_amdgcn_mfma_f32_16x16x32_bf16(af[i], bk[j], accK[i][j], 0, 0, 0);
            #pragma unroll
            for (int j = 0; j < 4; ++j)
                bv[j] = *(const bf16x8*)&Bvlds[(wn * 64 + j * 16 + li) * 64 + koff];
            #pragma unroll
            for (int i = 0; i < 4; ++i)
                #pragma unroll
                for (int j = 0; j < 4; ++j)
                    accV[i][j] = __builtin_amdgcn_mfma_f32_16x16x32_bf16(af[i], bv[j], accV[i][j], 0, 0, 0);
        }
    }
    #pragma unroll
    for (int fm = 0; fm < 4; ++fm) {
        #pragma unroll
        for (int fn = 0; fn < 4; ++fn) {
            int mrow = m0 + wm * 64 + fm * 16 + g * 4;
            int ncol = n0 + wn * 64 + fn * 16 + li;
            #pragma unroll
            for (int i = 0; i < 4; ++i) {
                size_t dst = ((size_t)b * HW + mrow + i) * C_DIM + ncol;
                OutK[dst] = f2b(accK[fm][fn][i]);
            }
            size_t dstv = ((size_t)b * C_DIM + ncol) * HW + mrow;
            short4 sv = make_short4(f2b(accV[fm][fn][0]), f2b(accV[fm][fn][1]),
                                    f2b(accV[fm][fn][2]), f2b(accV[fm][fn][3]));
            *(short4*)(OutV + dstv) = sv;
        }
    }
}

// ---------------- flash attention, round 8: fp8 QK path ----------------
// r7 structure (double-buffered KT=32, split waits) with K staged as fp8 e4m3
// (16KB/buf, kc-paired layout -> b128 reads feed TWO fp8 mfma steps) and Q
// held as fp8 register fragments. PV stays bf16 (unnormalized P overflows fp8).
#define KT 32
#define NTILES 64
__global__ __launch_bounds__(512, 2) void k_attn(
        const short* __restrict__ qT, const unsigned char* __restrict__ kT8,
        const short* __restrict__ vg, short* __restrict__ O0,
        short* __restrict__ O1, float* __restrict__ L0, float* __restrict__ L1)
{
    __shared__ __align__(16) short pool[73728];
    unsigned char* Kp8 = (unsigned char*)pool;  // 2 x 16384 B (chunk P = ccol*32+key)
    short* Vp = pool + 16384;                   // 2 x 20480 shorts (V: [ch][40] rows)
    short* Pp = pool + 57344;                   // 128 x 40 shorts  (P: 80B rows)

    int bid0 = blockIdx.x;
    int bid = (bid0 & 7) * 32 + (bid0 >> 3);    // XCD swizzle
    int qt = bid & 31, ks = (bid >> 5) & 1, b = bid >> 6;
    int m0 = qt * 128;
    int t = threadIdx.x, lane = t & 63, w = t >> 6;
    int g = lane >> 4, li = lane & 15;
    int l31 = lane & 31, l5 = lane >> 5;

    const unsigned char* kb8 = kT8 + ((size_t)b * HW + (size_t)ks * 2048) * 512;
    const short* vb = vg + (size_t)b * C_DIM * HW + ks * 2048;

    // Q fragments in fp8 (16 x 8B = 32 VGPR); channels kc*32 + g*8 + j
    long long qf8[16];
    {
        const short* qrow = qT + ((size_t)b * HW + m0 + w * 16 + li) * C_DIM;
        #pragma unroll
        for (int kc = 0; kc < 16; ++kc) {
            bf16x8 qv = *(const bf16x8*)&qrow[kc * 32 + g * 8];
            int lo = __builtin_amdgcn_cvt_pk_fp8_f32(b2f(qv[0]), b2f(qv[1]), 0, false);
            lo     = __builtin_amdgcn_cvt_pk_fp8_f32(b2f(qv[2]), b2f(qv[3]), lo, true);
            int hi = __builtin_amdgcn_cvt_pk_fp8_f32(b2f(qv[4]), b2f(qv[5]), 0, false);
            hi     = __builtin_amdgcn_cvt_pk_fp8_f32(b2f(qv[6]), b2f(qv[7]), hi, true);
            qf8[kc] = ((long long)(unsigned)hi << 32) | (unsigned)lo;
        }
    }
    f32x16 oacc[8];
    #pragma unroll
    for (int a = 0; a < 8; ++a) oacc[a] = zero16();
    float lsum = 0.f;

    // K staging source (chunk-transposed fp8): dest chunk D=t (+512): key=t&31, ccol=t>>5 (+16)
    const unsigned char* ksrc8 = kb8 + (size_t)(t & 31) * 512 + (t >> 5) * 16;
    // V staging: dest chunk D = r*512+t -> (ch=D/5, c=D%5); c==4 is pad
    int voff[5];
    #pragma unroll
    for (int r = 0; r < 5; ++r) {
        int D = r * 512 + t;
        int ch = D / 5;
        int c  = D - ch * 5;
        voff[r] = (c < 4) ? ch * 4096 + c * 8 : 0;
    }

    const float SC = 0.044194173824159216f * 1.4426950408889634f; // 512^-0.5 * log2(e)

    auto STAGE = [&](int buf, int nt) {
        int n0 = nt * KT;
        const unsigned char* kS = ksrc8 + (size_t)n0 * 512;
        unsigned char* kD = Kp8 + buf * 16384 + t * 16;
        gload16(kS, kD);
        gload16(kS + 256, kD + 8192);
        short* vD = Vp + buf * 20480 + t * 8;
        #pragma unroll
        for (int r = 0; r < 5; ++r)
            gload16(vb + voff[r] + n0, vD + r * 4096);
    };

    STAGE(0, 0);
    asm volatile("s_waitcnt vmcnt(0)" ::: "memory");
    __builtin_amdgcn_s_barrier();
    __builtin_amdgcn_sched_barrier(0);

    int buf = 0;
    for (int nt = 0; nt < NTILES; ++nt) {
        if (nt + 1 < NTILES) STAGE(buf ^ 1, nt + 1);   // prefetch: drains at tile-end

        // ---- QK fp8 (16x16x32, swapped: mfma(K, Q)) ----
        // addr = buf*16384 + kcp*2048 + fn*256 + g*512 + li*16; b128 = kc pair
        const unsigned char* kbase8 = Kp8 + buf * 16384 + g * 512 + li * 16;
        f32x4 s0[2], s1[2];
        s0[0] = zero4(); s0[1] = zero4(); s1[0] = zero4(); s1[1] = zero4();
        __builtin_amdgcn_s_setprio(1);
        #pragma unroll
        for (int kcp = 0; kcp < 8; ++kcp) {
            #pragma unroll
            for (int fn = 0; fn < 2; ++fn) {
                l64x2 kv = *(const l64x2*)&kbase8[kcp * 2048 + fn * 256];
                s0[fn] = __builtin_amdgcn_mfma_f32_16x16x32_fp8_fp8(kv[0], qf8[2 * kcp],     s0[fn], 0, 0, 0);
                s1[fn] = __builtin_amdgcn_mfma_f32_16x16x32_fp8_fp8(kv[1], qf8[2 * kcp + 1], s1[fn], 0, 0, 0);
            }
        }
        __builtin_amdgcn_s_setprio(0);
        // softmax (no-max) + P write: P[q = w*16+li][key = fn*16+g*4+i]
        #pragma unroll
        for (int fn = 0; fn < 2; ++fn) {
            float e0 = exp2f((s0[fn][0] + s1[fn][0]) * SC);
            float e1 = exp2f((s0[fn][1] + s1[fn][1]) * SC);
            float e2 = exp2f((s0[fn][2] + s1[fn][2]) * SC);
            float e3 = exp2f((s0[fn][3] + s1[fn][3]) * SC);
            lsum += (e0 + e1) + (e2 + e3);
            union { __hip_bfloat162 h; unsigned u; } p01, p23;
            p01.h = __float22bfloat162_rn(make_float2(e0, e1));
            p23.h = __float22bfloat162_rn(make_float2(e2, e3));
            *(uint2*)&Pp[(w * 16 + li) * 40 + fn * 16 + g * 4] = make_uint2(p01.u, p23.u);
        }

        // mid-tile barrier: P visible. LDS-only wait; prefetch stays in flight.
        asm volatile("s_waitcnt lgkmcnt(0)" ::: "memory");
        __builtin_amdgcn_s_barrier();
        __builtin_amdgcn_sched_barrier(0);

        // ---- PV bf16 (32x32x16): C[ch][q] += V[ch][k] * P[q][k] ----
        const short* vbase = Vp + buf * 20480 + (size_t)w * 64 * 40;
        bf16x8 vf[2][2];
        #pragma unroll
        for (int cht = 0; cht < 2; ++cht)
            #pragma unroll
            for (int kx = 0; kx < 2; ++kx)
                vf[cht][kx] = *(const bf16x8*)&vbase[(cht * 32 + l31) * 40 + kx * 16 + l5 * 8];
        __builtin_amdgcn_s_setprio(1);
        #pragma unroll
        for (int q2 = 0; q2 < 4; ++q2) {
            #pragma unroll
            for (int kx = 0; kx < 2; ++kx) {
                bf16x8 pf = *(const bf16x8*)&Pp[(q2 * 32 + l31) * 40 + kx * 16 + l5 * 8];
                oacc[q2 * 2 + 0] = __builtin_amdgcn_mfma_f32_32x32x16_bf16(vf[0][kx], pf, oacc[q2 * 2 + 0], 0, 0, 0);
                oacc[q2 * 2 + 1] = __builtin_amdgcn_mfma_f32_32x32x16_bf16(vf[1][kx], pf, oacc[q2 * 2 + 1], 0, 0, 0);
            }
        }
        __builtin_amdgcn_s_setprio(0);

        // tile-end barrier: prefetch STAGE(t+1) drained; Pp consumed by all waves.
        asm volatile("s_waitcnt vmcnt(0)" ::: "memory");
        __builtin_amdgcn_s_barrier();
        __builtin_amdgcn_sched_barrier(0);
        buf ^= 1;
    }

    // row-sum partials (wave w owns queries w*16..w*16+15; query = li)
    lsum += __shfl_xor(lsum, 16);
    lsum += __shfl_xor(lsum, 32);
    float* Lb = (ks ? L1 : L0) + (size_t)b * HW + m0 + w * 16;
    if (lane < 16) Lb[lane] = lsum;

    // O epilogue: per-wave LDS transpose (144B rows) -> coalesced [b][m][c]
    short* tp = pool + w * 9216;
    #pragma unroll
    for (int a = 0; a < 8; ++a) {
        int q2 = a >> 1, cht = a & 1;
        int q_l = q2 * 32 + l31;
        #pragma unroll
        for (int rq = 0; rq < 4; ++rq) {
            int chb = cht * 32 + rq * 8 + l5 * 4;
            union { __hip_bfloat162 h; unsigned u; } x01, x23;
            x01.h = __float22bfloat162_rn(make_float2(oacc[a][rq * 4 + 0], oacc[a][rq * 4 + 1]));
            x23.h = __float22bfloat162_rn(make_float2(oacc[a][rq * 4 + 2], oacc[a][rq * 4 + 3]));
            *(uint2*)&tp[q_l * 72 + chb] = make_uint2(x01.u, x23.u);
        }
    }
    asm volatile("s_waitcnt lgkmcnt(0)" ::: "memory");
    __builtin_amdgcn_sched_barrier(0);
    short* Ob = (ks ? O1 : O0) + ((size_t)b * HW + m0) * C_DIM + w * 64;
    #pragma unroll
    for (int qg = 0; qg < 16; ++qg) {
        int qr = qg * 8 + (lane >> 3);
        bf16x8 v = *(const bf16x8*)&tp[qr * 72 + (lane & 7) * 8];
        *(bf16x8*)&Ob[(size_t)qr * C_DIM + (lane & 7) * 8] = v;
    }
}

__global__ void k_att_comb(const short* __restrict__ O0, const short* __restrict__ O1,
                           const float* __restrict__ L0, const float* __restrict__ L1,
                           short* __restrict__ oatt) {
    int i = blockIdx.x * 256 + threadIdx.x;
    int row = i >> 6;
    int c0 = (i & 63) * 8;
    float r = 1.0f / (L0[row] + L1[row]);
    size_t base = (size_t)row * C_DIM + c0;
    bf16x8 a = *(const bf16x8*)&O0[base];
    bf16x8 c = *(const bf16x8*)&O1[base];
    bf16x8 o;
    #pragma unroll
    for (int j = 0; j < 8; ++j)
        o[j] = f2b((b2f(a[j]) + b2f(c[j])) * r);
    *(bf16x8*)&oatt[base] = o;
}

// ---------------- launch ----------------
extern "C" void kernel_launch(void* const* d_in, const int* in_sizes, int n_in,
                              void* d_out, int out_size, void* d_ws, size_t ws_size,
                              hipStream_t stream) {
    const float* x    = (const float*)d_in[0];
    const float* ln_w = (const float*)d_in[1];
    const float* ln_b = (const float*)d_in[2];
    const float* wq   = (const float*)d_in[3];
    const float* wk   = (const float*)d_in[4];
    const float* wv   = (const float*)d_in[5];
    const float* wp   = (const float*)d_in[6];
    const float* bp   = (const float*)d_in[7];
    float* out = (float*)d_out;

    char* ws = (char*)d_ws;
    size_t off = 0;
    auto alloc = [&](size_t bytes) {
        char* p = ws + off;
        off += (bytes + 255) & ~(size_t)255;
        return p;
    };
    short* hp   = (short*)alloc((size_t)BATCH * PPIX * C_DIM * 2);   // also O-partial 0
    short* wqb  = (short*)alloc((size_t)512 * 512 * 2);
    short* wkr  = (short*)alloc((size_t)512 * 4608 * 2);             // also kT8 (dead after kv conv)
    short* wvr  = (short*)alloc((size_t)512 * 4608 * 2);
    short* wpb  = (short*)alloc((size_t)512 * 512 * 2);
    short* qT   = (short*)alloc((size_t)BATCH * HW * C_DIM * 2);
    short* kT   = (short*)alloc((size_t)BATCH * HW * C_DIM * 2);
    short* vg   = (short*)alloc((size_t)BATCH * HW * C_DIM * 2);
    short* oatt = (short*)alloc((size_t)BATCH * HW * C_DIM * 2);     // also O-partial 1
    float* mean = (float*)alloc((size_t)BATCH * HW * 4);             // also Lsum 0
    float* rstd = (float*)alloc((size_t)BATCH * HW * 4);             // also Lsum 1

    hipMemsetAsync(hp, 0, (size_t)BATCH * PPIX * C_DIM * 2, stream);
    k_cvt_bf16<<<1024, 256, 0, stream>>>(wq, wqb, 512 * 512);
    k_cvt_bf16<<<1024, 256, 0, stream>>>(wp, wpb, 512 * 512);
    k_reorder_w3<<<9216, 256, 0, stream>>>(wk, wkr);
    k_reorder_w3<<<9216, 256, 0, stream>>>(wv, wvr);
    k_ln_stats<<<512, 256, 0, stream>>>(x, mean, rstd);
    k_ln_apply<<<2048, 256, 0, stream>>>(x, mean, rstd, ln_w, ln_b, hp);

    k_gemm<1, 0, 0><<<512, 256, 0, stream>>>(hp, wqb, qT, nullptr, nullptr);
    k_gemm_kv<<<512, 256, 0, stream>>>(hp, wkr, wvr, kT, vg);

    // wkr/wvr dead -> reuse the contiguous 9.4MB as the 8MB fp8 K buffer
    unsigned char* kT8 = (unsigned char*)wkr;
    k_cvt_k8<<<4096, 256, 0, stream>>>(kT, kT8);

    short* Op0 = hp;
    short* Op1 = oatt;
    float* Ls0 = mean;
    float* Ls1 = rstd;
    k_attn<<<256, 512, 0, stream>>>(qT, kT8, vg, Op0, Op1, Ls0, Ls1);
    k_att_comb<<<4096, 256, 0, stream>>>(Op0, Op1, Ls0, Ls1, oatt);

    k_gemm<1, 1, 2><<<512, 256, 0, stream>>>(oatt, wpb, out, bp, x);
}